// Round 2
// baseline (597.386 us; speedup 1.0000x reference)
//
#include <hip/hip_runtime.h>
#include <math.h>

#define TT 8192
#define BB 256
#define EE 8
#define KK 15
#define PI_F  3.14159265358979323846f
#define TPI_F 6.28318530717958647692f

// d_out flat layout (reference tuple order)
#define OFF_OUT 0
#define OFF_LAT (BB*TT)
#define OFF_SIG (OFF_LAT + BB*EE*TT)
#define OFF_P   (OFF_SIG + BB*EE*TT)
#define OFF_F   (OFF_P + BB*EE)
#define OFF_A   (OFF_F + BB*EE)
#define OFF_B0  (OFF_A + BB*EE)

#define TILE_C 1024

// swizzle for fft LDS only
#define SWZ(i) ((i) + ((i) >> 5))

// =====================================================================
// Kernel A: composed dilated conv, FULL-ROW polyphase LDS layout.
// One block per (e, b): 2048 blocks x 512 threads, dynamic LDS.
// sxp[ph*Lp + n] = x[-14d + ph + n*d]; a thread's 29-tap dilated window
// is CONTIGUOUS. Lp == 30 (mod 32): float2 window reads at lane-stride
// Lp tile all 32 banks (16 lanes x 2 banks) -> conflict-free ds_read_b64.
// Edge corrections are computed ENTIRELY from the thread's own win[]
// registers (index r+j+k <= 31, all compile-time) -> no hb buffers, no
// boundary phase, single barrier.
// LDS worst case (e=7): 128*94 + 96 = 12128 floats = 48512 B
// -> 3 blocks/CU resident, 24 waves/CU.
// =====================================================================
__global__ __launch_bounds__(512, 6) void conv_stack_kernel(
    const float* __restrict__ x, const float* __restrict__ W1,
    const float* __restrict__ b1, const float* __restrict__ W2,
    const float* __restrict__ b2, float* __restrict__ latent)
{
  extern __shared__ float smem[];
  const int e = blockIdx.x, b = blockIdx.y;
  const int d  = 1 << e;
  const int M  = TT >> e;                               // outputs per phase
  // smallest Lp >= M+28 with Lp == 30 (mod 32)
  const int Lp = ((((M - 2) + 31) >> 5) << 5) + 30;
  float* sxp = smem;                                    // d*Lp floats
  float* sW  = smem + d * Lp;                           // 96 floats
  const int tid = threadIdx.x;
  const float* xr = x + b * TT;

  // ---- stage full x row into polyphase layout (coalesced over i)
  const int nstage = TT + 28 * d;
  for (int i = tid; i < nstage; i += 512) {
    int t  = i - 14 * d;
    int ph = i & (d - 1);
    int n  = i >> e;
    sxp[ph * Lp + n] = (t >= 0 && t < TT) ? xr[t] : 0.0f;
  }

  // ---- weights: composed 29-tap + raw
  if (tid < 29) {
    float acc = 0.0f;
    for (int c = 0; c < 2; c++) {
      const float* w1 = W1 + e*30 + c*15;
      const float* w2 = W2 + e*30 + c*15;
      int jlo = tid - 14; if (jlo < 0) jlo = 0;
      int jhi = tid;      if (jhi > 14) jhi = 14;
      for (int j = jlo; j <= jhi; j++) acc += w2[j] * w1[tid - j];
    }
    sW[tid] = acc;
  } else if (tid == 29) {
    float s20 = 0.f, s21 = 0.f;
    for (int j = 0; j < 15; j++) { s20 += W2[e*30 + j]; s21 += W2[e*30 + 15 + j]; }
    sW[29] = b2[e] + s20*b1[e*2] + s21*b1[e*2 + 1];
  } else if (tid >= 32 && tid < 62) {
    sW[tid] = W1[e*30 + (tid - 32)];
  } else if (tid >= 64 && tid < 94) {
    sW[tid] = W2[e*30 + (tid - 64)];
  } else if (tid == 94 || tid == 95) {
    sW[tid] = b1[e*2 + (tid - 94)];
  }
  __syncthreads();

  float W[29];
  #pragma unroll
  for (int s = 0; s < 29; s++) W[s] = sW[s];
  const float Bc = sW[29];

  // ---- main composed conv: 4 groups of 4 chain outputs per thread
  float* lr = latent + (b * EE + e) * TT;
  #pragma unroll 1
  for (int g = 0; g < 4; g++) {
    const int vt = g * 512 + tid;            // virtual thread 0..2047
    const int ph = vt & (d - 1);
    const int m0 = (vt >> e) << 2;           // phase-local first output index
    const int row = ph * Lp;

    float win[32];
    {
      const float2* wp = (const float2*)&sxp[row + m0];
      #pragma unroll
      for (int v = 0; v < 16; v++) {
        float2 qv = wp[v];
        win[2*v] = qv.x; win[2*v+1] = qv.y;
      }
    }
    float acc[4] = {Bc, Bc, Bc, Bc};
    #pragma unroll
    for (int s = 0; s < 29; s++) {
      #pragma unroll
      for (int r = 0; r < 4; r++) acc[r] = fmaf(W[s], win[s + r], acc[r]);
    }

    // ---- first-edge correction (only reachable in group 0).
    // Output m<=6: subtract sum_j w2[j]*h~(taps from win, idx r+j+k<=23).
    if (g == 0 && m0 <= 6) {
      #pragma unroll
      for (int r = 0; r < 4; r++) {
        int m = m0 + r;
        if (m <= 6) {
          float corr = 0.0f;
          #pragma unroll
          for (int j = 0; j < 7; j++) {
            if (j <= 6 - m) {
              float h0 = sW[94], h1 = sW[95];
              #pragma unroll
              for (int k = 0; k < 15; k++) {
                float xv = win[r + j + k];
                h0 = fmaf(sW[32 + k], xv, h0);
                h1 = fmaf(sW[47 + k], xv, h1);
              }
              corr = fmaf(sW[64 + j], h0, corr);
              corr = fmaf(sW[79 + j], h1, corr);
            }
          }
          acc[r] -= corr;
        }
      }
    }
    // ---- last-edge correction (only reachable in group 3).
    // Output m>=M-7: taps j in [8,14], win idx r+j+k in [8,31].
    if (g == 3 && m0 + 3 >= M - 7) {
      #pragma unroll
      for (int r = 0; r < 4; r++) {
        int m = m0 + r;
        if (m >= M - 7) {
          float corr = 0.0f;
          #pragma unroll
          for (int jj = 0; jj < 7; jj++) {
            const int j = 8 + jj;
            if (m + j >= M + 7) {
              float h0 = sW[94], h1 = sW[95];
              #pragma unroll
              for (int k = 0; k < 15; k++) {
                float xv = win[r + j + k];
                h0 = fmaf(sW[32 + k], xv, h0);
                h1 = fmaf(sW[47 + k], xv, h1);
              }
              corr = fmaf(sW[64 + j], h0, corr);
              corr = fmaf(sW[79 + j], h1, corr);
            }
          }
          acc[r] -= corr;
        }
      }
    }

    #pragma unroll
    for (int r = 0; r < 4; r++) lr[ph + (m0 + r) * d] = acc[r];
  }
}

// =====================================================================
// Kernel B: real-packed FFT (N=4096 radix-4) + moments + fc phase.
// 512 threads; native __sinf/__cosf only (no slow-path sincos).
// =====================================================================
#define NF 4096

__device__ __forceinline__ int rev4(int k) {   // base-4 digit reversal, 6 digits
  unsigned r = __brev((unsigned)k) >> 20;      // 12-bit bit reversal
  return (int)(((r & 0x555u) << 1) | ((r >> 1) & 0x555u));
}

__global__ __launch_bounds__(512) void fft_kernel(
    const float* __restrict__ latent, const float* __restrict__ fcW,
    const float* __restrict__ fcb, float* __restrict__ outP,
    float* __restrict__ outF, float* __restrict__ outA, float* __restrict__ outB0)
{
  __shared__ float re[SWZ(NF - 1) + 1];
  __shared__ float im[SWZ(NF - 1) + 1];
  __shared__ float rbuf[32];
  const int e = blockIdx.x, b = blockIdx.y, tid = threadIdx.x;
  const float2* row2 = (const float2*)(latent + (b*EE + e)*TT);
  const float2* f02  = (const float2*)(fcW + (e*2 + 0)*TT);
  const float2* f12  = (const float2*)(fcW + (e*2 + 1)*TT);

  float v0 = 0.f, v1 = 0.f;
  for (int n = tid; n < NF; n += 512) {
    float2 z = row2[n];
    re[SWZ(n)] = z.x; im[SWZ(n)] = z.y;
    float2 a0 = f02[n], a1 = f12[n];
    v0 = fmaf(z.x, a0.x, v0); v0 = fmaf(z.y, a0.y, v0);
    v1 = fmaf(z.x, a1.x, v1); v1 = fmaf(z.y, a1.y, v1);
  }
  __syncthreads();

  for (int L = NF >> 2; L >= 1; L >>= 2) {
    float wstep = -1.57079632679f / (float)L;
    for (int u = tid; u < (NF >> 2); u += 512) {
      int p = u & (L - 1);
      int base = ((u - p) << 2) + p;
      int i0 = SWZ(base), i1 = SWZ(base + L), i2 = SWZ(base + 2*L), i3 = SWZ(base + 3*L);
      float ar = re[i0], ai = im[i0];
      float br = re[i1], bi = im[i1];
      float cr = re[i2], ci = im[i2];
      float dr = re[i3], di = im[i3];
      float t0r = ar + cr, t0i = ai + ci;
      float t1r = ar - cr, t1i = ai - ci;
      float t2r = br + dr, t2i = bi + di;
      float t3r = br - dr, t3i = bi - di;
      float A0r = t0r + t2r, A0i = t0i + t2i;
      float A1r = t1r + t3i, A1i = t1i - t3r;
      float A2r = t0r - t2r, A2i = t0i - t2i;
      float A3r = t1r - t3i, A3i = t1i + t3r;
      float ang = wstep * (float)p;
      float s1 = __sinf(ang), c1 = __cosf(ang);
      float c2 = c1*c1 - s1*s1, s2 = 2.f*c1*s1;
      float c3 = c1*c2 - s1*s2, s3 = c1*s2 + s1*c2;
      re[i0] = A0r;                 im[i0] = A0i;
      re[i1] = A1r*c1 - A1i*s1;     im[i1] = A1r*s1 + A1i*c1;
      re[i2] = A2r*c2 - A2i*s2;     im[i2] = A2r*s2 + A2i*c2;
      re[i3] = A3r*c3 - A3i*s3;     im[i3] = A3r*s3 + A3i*c3;
    }
    __syncthreads();
  }

  float pacc = 0.f, facc = 0.f;
  for (int k = 1 + tid; k < NF; k += 512) {
    int jk = SWZ(rev4(k));
    int jm = SWZ(rev4(NF - k));
    float zr = re[jk], zi = im[jk];
    float yr = re[jm], yi = im[jm];
    float Er = 0.5f*(zr + yr), Ei = 0.5f*(zi - yi);
    float Dr = 0.5f*(zr - yr), Di = 0.5f*(zi + yi);
    float Or = Di, Oi = -Dr;
    float ang = -PI_F * (float)k / (float)NF;
    float s = __sinf(ang), c = __cosf(ang);
    float Xr = Er + c*Or - s*Oi;
    float Xi = Ei + c*Oi + s*Or;
    float mag = fmaf(Xr, Xr, Xi*Xi);
    pacc += mag;
    facc = fmaf(0.5f * (float)k, mag, facc);
  }
  if (tid == 0) {
    float X = re[SWZ(0)] - im[SWZ(0)];
    pacc += X*X;
    facc += 2048.0f * X*X;
  }

  #pragma unroll
  for (int off = 32; off > 0; off >>= 1) {
    pacc += __shfl_down(pacc, off);
    facc += __shfl_down(facc, off);
    v0   += __shfl_down(v0, off);
    v1   += __shfl_down(v1, off);
  }
  int wid = tid >> 6, lane = tid & 63;
  if (lane == 0) {
    rbuf[wid*4 + 0] = pacc; rbuf[wid*4 + 1] = facc;
    rbuf[wid*4 + 2] = v0;   rbuf[wid*4 + 3] = v1;
  }
  __syncthreads();
  if (tid == 0) {
    float P = 0.f, Fw = 0.f, V0 = 0.f, V1 = 0.f;
    #pragma unroll
    for (int w = 0; w < 8; w++) {
      P += rbuf[w*4]; Fw += rbuf[w*4+1]; V0 += rbuf[w*4+2]; V1 += rbuf[w*4+3];
    }
    float z0r = re[SWZ(0)], z0i = im[SWZ(0)];
    float amp  = 2.0f * sqrtf(P) / (float)TT;
    float boff = (z0r + z0i) / (float)TT;
    float vv0 = V0 + fcb[e*2 + 0];
    float vv1 = V1 + fcb[e*2 + 1];
    float ph  = atan2f(vv1, vv0) / TPI_F;
    int idx = b*EE + e;
    outP[idx]  = ph;
    outF[idx]  = Fw / P;
    outA[idx]  = amp;
    outB0[idx] = boff;
  }
}

// =====================================================================
// Kernel C: sinusoid reconstruction + fused deconv tree.
// =====================================================================
#define SST 1068
#define SL0 1056
#define SL1 1040

__global__ __launch_bounds__(256) void sig_deconv_kernel(
    const float* __restrict__ Pv, const float* __restrict__ Fv,
    const float* __restrict__ Av, const float* __restrict__ B0v,
    const float* __restrict__ dW0, const float* __restrict__ db0,
    const float* __restrict__ dW1, const float* __restrict__ db1,
    const float* __restrict__ dW2, const float* __restrict__ db2,
    float* __restrict__ sig, float* __restrict__ out)
{
  __shared__ float smem[4*SL0 + 8*SST];
  float* sl0  = smem;
  float* ssig = smem + 4*SL0;
  float* sl1  = smem + 4*SL0;   // overlays ssig after level 0

  const int tile = blockIdx.x, b = blockIdx.y;
  const int t0 = tile * TILE_C;
  const int tid = threadIdx.x;
  const float step = 2.0f / 8191.0f;

  // ---- per-channel params (uniform -> SGPRs)
  float fs[8], am[8], psh[8], bo[8];
  #pragma unroll
  for (int ch = 0; ch < EE; ch++) {
    int idx = b*EE + ch;
    fs[ch] = Fv[idx]; am[ch] = Av[idx]; psh[ch] = Pv[idx]; bo[ch] = B0v[idx];
  }

  // ---- sinusoid generation, all channels in one flattened loop
  for (int i = tid; i < SST; i += 256) {
    int t = t0 + i - 21;
    bool in = (i < 1066 && t >= 0 && t < TT);
    float arg = fmaf(step, (float)t, -1.0f);
    bool wr = (i >= 21 && i < 21 + TILE_C);
    #pragma unroll
    for (int ch = 0; ch < EE; ch++) {
      float rr = fmaf(fs[ch], arg, psh[ch]);
      rr -= rintf(rr);
      float val = in ? fmaf(am[ch], __sinf(TPI_F * rr), bo[ch]) : 0.0f;
      ssig[ch*SST + i] = val;
      if (wr) sig[(b*EE + ch)*TT + t] = val;
    }
  }
  __syncthreads();

  // ---- level 0: 8 -> 4 channels
  for (int g = 0; g < 4; g++) {
    float bg = db0[g];
    for (int u = tid; u < 263; u += 256) {
      const float4* p0 = (const float4*)(ssig + (2*g)*SST + 4*u);
      const float4* p1 = (const float4*)(ssig + (2*g+1)*SST + 4*u);
      float w0[20], w1[20];
      #pragma unroll
      for (int v = 0; v < 5; v++) {
        float4 q0 = p0[v], q1 = p1[v];
        w0[4*v]=q0.x; w0[4*v+1]=q0.y; w0[4*v+2]=q0.z; w0[4*v+3]=q0.w;
        w1[4*v]=q1.x; w1[4*v+1]=q1.y; w1[4*v+2]=q1.z; w1[4*v+3]=q1.w;
      }
      #pragma unroll
      for (int r = 0; r < 4; r++) {
        int i0 = 4*u + r;
        int t = t0 + i0 - 14;
        float a2 = bg;
        #pragma unroll
        for (int k = 0; k < KK; k++) {
          a2 = fmaf(dW0[g*30 + k],      w0[r + k], a2);
          a2 = fmaf(dW0[g*30 + 15 + k], w1[r + k], a2);
        }
        sl0[g*SL0 + i0] = (t >= 0 && t < TT) ? a2 : 0.0f;
      }
    }
  }
  if (tid < 16) sl0[(tid >> 2)*SL0 + 1052 + (tid & 3)] = 0.0f;
  __syncthreads();

  // ---- level 1: 4 -> 2 channels
  for (int g = 0; g < 2; g++) {
    float bg = db1[g];
    for (int u = tid; u < 260; u += 256) {
      const float4* p0 = (const float4*)(sl0 + (2*g)*SL0 + 4*u);
      const float4* p1 = (const float4*)(sl0 + (2*g+1)*SL0 + 4*u);
      float w0[20], w1[20];
      #pragma unroll
      for (int v = 0; v < 5; v++) {
        float4 q0 = p0[v], q1 = p1[v];
        w0[4*v]=q0.x; w0[4*v+1]=q0.y; w0[4*v+2]=q0.z; w0[4*v+3]=q0.w;
        w1[4*v]=q1.x; w1[4*v+1]=q1.y; w1[4*v+2]=q1.z; w1[4*v+3]=q1.w;
      }
      #pragma unroll
      for (int r = 0; r < 4; r++) {
        int i1 = 4*u + r;
        if (i1 < 1038) {
          int t = t0 + i1 - 7;
          float a2 = bg;
          #pragma unroll
          for (int k = 0; k < KK; k++) {
            a2 = fmaf(dW1[g*30 + k],      w0[r + k], a2);
            a2 = fmaf(dW1[g*30 + 15 + k], w1[r + k], a2);
          }
          sl1[g*SL1 + i1] = (t >= 0 && t < TT) ? a2 : 0.0f;
        }
      }
    }
  }
  __syncthreads();

  // ---- level 2: 2 -> 1 channel
  {
    float bg = db2[0];
    float* orow = out + b*TT + t0;
    int u = tid;
    const float4* p0 = (const float4*)(sl1 + 4*u);
    const float4* p1 = (const float4*)(sl1 + SL1 + 4*u);
    float w0[20], w1[20];
    #pragma unroll
    for (int v = 0; v < 5; v++) {
      float4 q0 = p0[v], q1 = p1[v];
      w0[4*v]=q0.x; w0[4*v+1]=q0.y; w0[4*v+2]=q0.z; w0[4*v+3]=q0.w;
      w1[4*v]=q1.x; w1[4*v+1]=q1.y; w1[4*v+2]=q1.z; w1[4*v+3]=q1.w;
    }
    float4 res;
    float* resf = (float*)&res;
    #pragma unroll
    for (int r = 0; r < 4; r++) {
      float a2 = bg;
      #pragma unroll
      for (int k = 0; k < KK; k++) {
        a2 = fmaf(dW2[k],      w0[r + k], a2);
        a2 = fmaf(dW2[15 + k], w1[r + k], a2);
      }
      resf[r] = a2;
    }
    ((float4*)orow)[u] = res;
  }
}

extern "C" void kernel_launch(void* const* d_in, const int* in_sizes, int n_in,
                              void* d_out, int out_size, void* d_ws, size_t ws_size,
                              hipStream_t stream) {
  const float* x   = (const float*)d_in[0];
  const float* W1  = (const float*)d_in[1];
  const float* b1  = (const float*)d_in[2];
  const float* W2  = (const float*)d_in[3];
  const float* b2  = (const float*)d_in[4];
  const float* fcW = (const float*)d_in[5];
  const float* fcb = (const float*)d_in[6];
  const float* dW0 = (const float*)d_in[7];
  const float* db0 = (const float*)d_in[8];
  const float* dW1 = (const float*)d_in[9];
  const float* db1 = (const float*)d_in[10];
  const float* dW2 = (const float*)d_in[11];
  const float* db2 = (const float*)d_in[12];

  float* o        = (float*)d_out;
  float* out_main = o + OFF_OUT;
  float* latent   = o + OFF_LAT;
  float* sig      = o + OFF_SIG;
  float* pP  = o + OFF_P;
  float* pF  = o + OFF_F;
  float* pA  = o + OFF_A;
  float* pB0 = o + OFF_B0;

  // dynamic LDS: worst case e=7 -> 128*94 + 96 = 12128 floats = 48512 B
  const size_t lds_conv = 12128 * sizeof(float);   // -> 3 blocks/CU
  conv_stack_kernel<<<dim3(EE, BB), 512, lds_conv, stream>>>(x, W1, b1, W2, b2, latent);
  fft_kernel<<<dim3(EE, BB), 512, 0, stream>>>(latent, fcW, fcb, pP, pF, pA, pB0);
  sig_deconv_kernel<<<dim3(TT/TILE_C, BB), 256, 0, stream>>>(
      pP, pF, pA, pB0, dW0, db0, dW1, db1, dW2, db2, sig, out_main);
}

// Round 3
// 353.228 us; speedup vs baseline: 1.6912x; 1.6912x over previous
//
#include <hip/hip_runtime.h>
#include <math.h>

#define TT 8192
#define BB 256
#define EE 8
#define KK 15
#define PI_F  3.14159265358979323846f
#define TPI_F 6.28318530717958647692f

// d_out flat layout (reference tuple order)
#define OFF_OUT 0
#define OFF_LAT (BB*TT)
#define OFF_SIG (OFF_LAT + BB*EE*TT)
#define OFF_P   (OFF_SIG + BB*EE*TT)
#define OFF_F   (OFF_P + BB*EE)
#define OFF_A   (OFF_F + BB*EE)
#define OFF_B0  (OFF_A + BB*EE)

#define TILE_C 1024

// swizzle for fft LDS only
#define SWZ(i) ((i) + ((i) >> 5))

// =====================================================================
// Kernel A: composed dilated conv, FULL-ROW polyphase LDS layout.
// One block per (e, b): 2048 blocks x 512 threads, dynamic LDS.
// sxp[ph*Lp + n] = x[-14d + ph + n*d]; a thread's 29-tap dilated window
// is CONTIGUOUS. Lp == 30 (mod 32): conflict-light staging writes and
// float2 window reads (measured: conflicts 1.54e7 -> 6.4e6).
// Edge corrections from the thread's own win[] registers; h~ shared
// across (r,j) via s=r+j (static indices only -> registers, no scratch).
// NO min-occupancy launch bound: R2's (512,6) cap caused catastrophic
// scratch spill (VGPR 40, 1.4 GB spill traffic). Peak demand ~95 VGPR.
// LDS worst case (e=7): 128*94 + 96 = 12128 floats = 48512 B.
// =====================================================================
__global__ __launch_bounds__(512) void conv_stack_kernel(
    const float* __restrict__ x, const float* __restrict__ W1,
    const float* __restrict__ b1, const float* __restrict__ W2,
    const float* __restrict__ b2, float* __restrict__ latent)
{
  extern __shared__ float smem[];
  const int e = blockIdx.x, b = blockIdx.y;
  const int d  = 1 << e;
  const int M  = TT >> e;                               // outputs per phase
  // smallest Lp >= M+28 with Lp == 30 (mod 32)
  const int Lp = ((((M - 2) + 31) >> 5) << 5) + 30;
  float* sxp = smem;                                    // d*Lp floats
  float* sW  = smem + d * Lp;                           // 96 floats
  const int tid = threadIdx.x;
  const float* xr = x + b * TT;

  // ---- stage full x row into polyphase layout (coalesced over i)
  const int nstage = TT + 28 * d;
  for (int i = tid; i < nstage; i += 512) {
    int t  = i - 14 * d;
    int ph = i & (d - 1);
    int n  = i >> e;
    sxp[ph * Lp + n] = (t >= 0 && t < TT) ? xr[t] : 0.0f;
  }

  // ---- weights: composed 29-tap + raw
  if (tid < 29) {
    float acc = 0.0f;
    for (int c = 0; c < 2; c++) {
      const float* w1 = W1 + e*30 + c*15;
      const float* w2 = W2 + e*30 + c*15;
      int jlo = tid - 14; if (jlo < 0) jlo = 0;
      int jhi = tid;      if (jhi > 14) jhi = 14;
      for (int j = jlo; j <= jhi; j++) acc += w2[j] * w1[tid - j];
    }
    sW[tid] = acc;
  } else if (tid == 29) {
    float s20 = 0.f, s21 = 0.f;
    for (int j = 0; j < 15; j++) { s20 += W2[e*30 + j]; s21 += W2[e*30 + 15 + j]; }
    sW[29] = b2[e] + s20*b1[e*2] + s21*b1[e*2 + 1];
  } else if (tid >= 32 && tid < 62) {
    sW[tid] = W1[e*30 + (tid - 32)];
  } else if (tid >= 64 && tid < 94) {
    sW[tid] = W2[e*30 + (tid - 64)];
  } else if (tid == 94 || tid == 95) {
    sW[tid] = b1[e*2 + (tid - 94)];
  }
  __syncthreads();

  float W[29];
  #pragma unroll
  for (int s = 0; s < 29; s++) W[s] = sW[s];
  const float Bc = sW[29];

  // ---- main composed conv: 4 groups of 4 chain outputs per thread
  float* lr = latent + (b * EE + e) * TT;
  #pragma unroll 1
  for (int g = 0; g < 4; g++) {
    const int vt = g * 512 + tid;            // virtual thread 0..2047
    const int ph = vt & (d - 1);
    const int m0 = (vt >> e) << 2;           // phase-local first output index
    const int row = ph * Lp;

    float win[32];
    {
      const float2* wp = (const float2*)&sxp[row + m0];
      #pragma unroll
      for (int v = 0; v < 16; v++) {
        float2 qv = wp[v];
        win[2*v] = qv.x; win[2*v+1] = qv.y;
      }
    }
    float acc[4] = {Bc, Bc, Bc, Bc};
    #pragma unroll
    for (int s = 0; s < 29; s++) {
      #pragma unroll
      for (int r = 0; r < 4; r++) acc[r] = fmaf(W[s], win[s + r], acc[r]);
    }

    // ---- first-edge correction (only reachable in group 0).
    // corr[r] = sum_{j<=6-m} w2[j]*h~(s=r+j); h~ shared across (r,j).
    if (g == 0 && m0 <= 6) {
      float h0[10], h1[10];
      #pragma unroll
      for (int s = 0; s < 10; s++) {
        float a0 = sW[94], a1 = sW[95];
        #pragma unroll
        for (int k = 0; k < 15; k++) {
          float xv = win[s + k];
          a0 = fmaf(sW[32 + k], xv, a0);
          a1 = fmaf(sW[47 + k], xv, a1);
        }
        h0[s] = a0; h1[s] = a1;
      }
      #pragma unroll
      for (int r = 0; r < 4; r++) {
        float corr = 0.0f;
        #pragma unroll
        for (int j = 0; j < 7; j++) {
          if (m0 + r + j <= 6) {
            corr = fmaf(sW[64 + j], h0[r + j], corr);
            corr = fmaf(sW[79 + j], h1[r + j], corr);
          }
        }
        acc[r] -= corr;
      }
    }
    // ---- last-edge correction (only reachable in group 3).
    // taps j in [8,14], h~ at s=r+j in [8,17] (stored at s-8).
    if (g == 3 && m0 + 3 >= M - 7) {
      float h0[10], h1[10];
      #pragma unroll
      for (int s = 0; s < 10; s++) {
        float a0 = sW[94], a1 = sW[95];
        #pragma unroll
        for (int k = 0; k < 15; k++) {
          float xv = win[8 + s + k];
          a0 = fmaf(sW[32 + k], xv, a0);
          a1 = fmaf(sW[47 + k], xv, a1);
        }
        h0[s] = a0; h1[s] = a1;
      }
      #pragma unroll
      for (int r = 0; r < 4; r++) {
        float corr = 0.0f;
        #pragma unroll
        for (int jj = 0; jj < 7; jj++) {
          const int j = 8 + jj;
          if (m0 + r + j >= M + 7) {
            corr = fmaf(sW[64 + j], h0[r + jj], corr);
            corr = fmaf(sW[79 + j], h1[r + jj], corr);
          }
        }
        acc[r] -= corr;
      }
    }

    #pragma unroll
    for (int r = 0; r < 4; r++) lr[ph + (m0 + r) * d] = acc[r];
  }
}

// =====================================================================
// Kernel B: real-packed FFT (N=4096 radix-4) + moments + fc phase.
// 512 threads; native __sinf/__cosf only (no slow-path sincos).
// =====================================================================
#define NF 4096

__device__ __forceinline__ int rev4(int k) {   // base-4 digit reversal, 6 digits
  unsigned r = __brev((unsigned)k) >> 20;      // 12-bit bit reversal
  return (int)(((r & 0x555u) << 1) | ((r >> 1) & 0x555u));
}

__global__ __launch_bounds__(512) void fft_kernel(
    const float* __restrict__ latent, const float* __restrict__ fcW,
    const float* __restrict__ fcb, float* __restrict__ outP,
    float* __restrict__ outF, float* __restrict__ outA, float* __restrict__ outB0)
{
  __shared__ float re[SWZ(NF - 1) + 1];
  __shared__ float im[SWZ(NF - 1) + 1];
  __shared__ float rbuf[32];
  const int e = blockIdx.x, b = blockIdx.y, tid = threadIdx.x;
  const float2* row2 = (const float2*)(latent + (b*EE + e)*TT);
  const float2* f02  = (const float2*)(fcW + (e*2 + 0)*TT);
  const float2* f12  = (const float2*)(fcW + (e*2 + 1)*TT);

  float v0 = 0.f, v1 = 0.f;
  for (int n = tid; n < NF; n += 512) {
    float2 z = row2[n];
    re[SWZ(n)] = z.x; im[SWZ(n)] = z.y;
    float2 a0 = f02[n], a1 = f12[n];
    v0 = fmaf(z.x, a0.x, v0); v0 = fmaf(z.y, a0.y, v0);
    v1 = fmaf(z.x, a1.x, v1); v1 = fmaf(z.y, a1.y, v1);
  }
  __syncthreads();

  for (int L = NF >> 2; L >= 1; L >>= 2) {
    float wstep = -1.57079632679f / (float)L;
    for (int u = tid; u < (NF >> 2); u += 512) {
      int p = u & (L - 1);
      int base = ((u - p) << 2) + p;
      int i0 = SWZ(base), i1 = SWZ(base + L), i2 = SWZ(base + 2*L), i3 = SWZ(base + 3*L);
      float ar = re[i0], ai = im[i0];
      float br = re[i1], bi = im[i1];
      float cr = re[i2], ci = im[i2];
      float dr = re[i3], di = im[i3];
      float t0r = ar + cr, t0i = ai + ci;
      float t1r = ar - cr, t1i = ai - ci;
      float t2r = br + dr, t2i = bi + di;
      float t3r = br - dr, t3i = bi - di;
      float A0r = t0r + t2r, A0i = t0i + t2i;
      float A1r = t1r + t3i, A1i = t1i - t3r;
      float A2r = t0r - t2r, A2i = t0i - t2i;
      float A3r = t1r - t3i, A3i = t1i + t3r;
      float ang = wstep * (float)p;
      float s1 = __sinf(ang), c1 = __cosf(ang);
      float c2 = c1*c1 - s1*s1, s2 = 2.f*c1*s1;
      float c3 = c1*c2 - s1*s2, s3 = c1*s2 + s1*c2;
      re[i0] = A0r;                 im[i0] = A0i;
      re[i1] = A1r*c1 - A1i*s1;     im[i1] = A1r*s1 + A1i*c1;
      re[i2] = A2r*c2 - A2i*s2;     im[i2] = A2r*s2 + A2i*c2;
      re[i3] = A3r*c3 - A3i*s3;     im[i3] = A3r*s3 + A3i*c3;
    }
    __syncthreads();
  }

  float pacc = 0.f, facc = 0.f;
  for (int k = 1 + tid; k < NF; k += 512) {
    int jk = SWZ(rev4(k));
    int jm = SWZ(rev4(NF - k));
    float zr = re[jk], zi = im[jk];
    float yr = re[jm], yi = im[jm];
    float Er = 0.5f*(zr + yr), Ei = 0.5f*(zi - yi);
    float Dr = 0.5f*(zr - yr), Di = 0.5f*(zi + yi);
    float Or = Di, Oi = -Dr;
    float ang = -PI_F * (float)k / (float)NF;
    float s = __sinf(ang), c = __cosf(ang);
    float Xr = Er + c*Or - s*Oi;
    float Xi = Ei + c*Oi + s*Or;
    float mag = fmaf(Xr, Xr, Xi*Xi);
    pacc += mag;
    facc = fmaf(0.5f * (float)k, mag, facc);
  }
  if (tid == 0) {
    float X = re[SWZ(0)] - im[SWZ(0)];
    pacc += X*X;
    facc += 2048.0f * X*X;
  }

  #pragma unroll
  for (int off = 32; off > 0; off >>= 1) {
    pacc += __shfl_down(pacc, off);
    facc += __shfl_down(facc, off);
    v0   += __shfl_down(v0, off);
    v1   += __shfl_down(v1, off);
  }
  int wid = tid >> 6, lane = tid & 63;
  if (lane == 0) {
    rbuf[wid*4 + 0] = pacc; rbuf[wid*4 + 1] = facc;
    rbuf[wid*4 + 2] = v0;   rbuf[wid*4 + 3] = v1;
  }
  __syncthreads();
  if (tid == 0) {
    float P = 0.f, Fw = 0.f, V0 = 0.f, V1 = 0.f;
    #pragma unroll
    for (int w = 0; w < 8; w++) {
      P += rbuf[w*4]; Fw += rbuf[w*4+1]; V0 += rbuf[w*4+2]; V1 += rbuf[w*4+3];
    }
    float z0r = re[SWZ(0)], z0i = im[SWZ(0)];
    float amp  = 2.0f * sqrtf(P) / (float)TT;
    float boff = (z0r + z0i) / (float)TT;
    float vv0 = V0 + fcb[e*2 + 0];
    float vv1 = V1 + fcb[e*2 + 1];
    float ph  = atan2f(vv1, vv0) / TPI_F;
    int idx = b*EE + e;
    outP[idx]  = ph;
    outF[idx]  = Fw / P;
    outA[idx]  = amp;
    outB0[idx] = boff;
  }
}

// =====================================================================
// Kernel C: sinusoid reconstruction + fused deconv tree.
// =====================================================================
#define SST 1068
#define SL0 1056
#define SL1 1040

__global__ __launch_bounds__(256) void sig_deconv_kernel(
    const float* __restrict__ Pv, const float* __restrict__ Fv,
    const float* __restrict__ Av, const float* __restrict__ B0v,
    const float* __restrict__ dW0, const float* __restrict__ db0,
    const float* __restrict__ dW1, const float* __restrict__ db1,
    const float* __restrict__ dW2, const float* __restrict__ db2,
    float* __restrict__ sig, float* __restrict__ out)
{
  __shared__ float smem[4*SL0 + 8*SST];
  float* sl0  = smem;
  float* ssig = smem + 4*SL0;
  float* sl1  = smem + 4*SL0;   // overlays ssig after level 0

  const int tile = blockIdx.x, b = blockIdx.y;
  const int t0 = tile * TILE_C;
  const int tid = threadIdx.x;
  const float step = 2.0f / 8191.0f;

  // ---- per-channel params (uniform -> SGPRs)
  float fs[8], am[8], psh[8], bo[8];
  #pragma unroll
  for (int ch = 0; ch < EE; ch++) {
    int idx = b*EE + ch;
    fs[ch] = Fv[idx]; am[ch] = Av[idx]; psh[ch] = Pv[idx]; bo[ch] = B0v[idx];
  }

  // ---- sinusoid generation, all channels in one flattened loop
  for (int i = tid; i < SST; i += 256) {
    int t = t0 + i - 21;
    bool in = (i < 1066 && t >= 0 && t < TT);
    float arg = fmaf(step, (float)t, -1.0f);
    bool wr = (i >= 21 && i < 21 + TILE_C);
    #pragma unroll
    for (int ch = 0; ch < EE; ch++) {
      float rr = fmaf(fs[ch], arg, psh[ch]);
      rr -= rintf(rr);
      float val = in ? fmaf(am[ch], __sinf(TPI_F * rr), bo[ch]) : 0.0f;
      ssig[ch*SST + i] = val;
      if (wr) sig[(b*EE + ch)*TT + t] = val;
    }
  }
  __syncthreads();

  // ---- level 0: 8 -> 4 channels
  for (int g = 0; g < 4; g++) {
    float bg = db0[g];
    for (int u = tid; u < 263; u += 256) {
      const float4* p0 = (const float4*)(ssig + (2*g)*SST + 4*u);
      const float4* p1 = (const float4*)(ssig + (2*g+1)*SST + 4*u);
      float w0[20], w1[20];
      #pragma unroll
      for (int v = 0; v < 5; v++) {
        float4 q0 = p0[v], q1 = p1[v];
        w0[4*v]=q0.x; w0[4*v+1]=q0.y; w0[4*v+2]=q0.z; w0[4*v+3]=q0.w;
        w1[4*v]=q1.x; w1[4*v+1]=q1.y; w1[4*v+2]=q1.z; w1[4*v+3]=q1.w;
      }
      #pragma unroll
      for (int r = 0; r < 4; r++) {
        int i0 = 4*u + r;
        int t = t0 + i0 - 14;
        float a2 = bg;
        #pragma unroll
        for (int k = 0; k < KK; k++) {
          a2 = fmaf(dW0[g*30 + k],      w0[r + k], a2);
          a2 = fmaf(dW0[g*30 + 15 + k], w1[r + k], a2);
        }
        sl0[g*SL0 + i0] = (t >= 0 && t < TT) ? a2 : 0.0f;
      }
    }
  }
  if (tid < 16) sl0[(tid >> 2)*SL0 + 1052 + (tid & 3)] = 0.0f;
  __syncthreads();

  // ---- level 1: 4 -> 2 channels
  for (int g = 0; g < 2; g++) {
    float bg = db1[g];
    for (int u = tid; u < 260; u += 256) {
      const float4* p0 = (const float4*)(sl0 + (2*g)*SL0 + 4*u);
      const float4* p1 = (const float4*)(sl0 + (2*g+1)*SL0 + 4*u);
      float w0[20], w1[20];
      #pragma unroll
      for (int v = 0; v < 5; v++) {
        float4 q0 = p0[v], q1 = p1[v];
        w0[4*v]=q0.x; w0[4*v+1]=q0.y; w0[4*v+2]=q0.z; w0[4*v+3]=q0.w;
        w1[4*v]=q1.x; w1[4*v+1]=q1.y; w1[4*v+2]=q1.z; w1[4*v+3]=q1.w;
      }
      #pragma unroll
      for (int r = 0; r < 4; r++) {
        int i1 = 4*u + r;
        if (i1 < 1038) {
          int t = t0 + i1 - 7;
          float a2 = bg;
          #pragma unroll
          for (int k = 0; k < KK; k++) {
            a2 = fmaf(dW1[g*30 + k],      w0[r + k], a2);
            a2 = fmaf(dW1[g*30 + 15 + k], w1[r + k], a2);
          }
          sl1[g*SL1 + i1] = (t >= 0 && t < TT) ? a2 : 0.0f;
        }
      }
    }
  }
  __syncthreads();

  // ---- level 2: 2 -> 1 channel
  {
    float bg = db2[0];
    float* orow = out + b*TT + t0;
    int u = tid;
    const float4* p0 = (const float4*)(sl1 + 4*u);
    const float4* p1 = (const float4*)(sl1 + SL1 + 4*u);
    float w0[20], w1[20];
    #pragma unroll
    for (int v = 0; v < 5; v++) {
      float4 q0 = p0[v], q1 = p1[v];
      w0[4*v]=q0.x; w0[4*v+1]=q0.y; w0[4*v+2]=q0.z; w0[4*v+3]=q0.w;
      w1[4*v]=q1.x; w1[4*v+1]=q1.y; w1[4*v+2]=q1.z; w1[4*v+3]=q1.w;
    }
    float4 res;
    float* resf = (float*)&res;
    #pragma unroll
    for (int r = 0; r < 4; r++) {
      float a2 = bg;
      #pragma unroll
      for (int k = 0; k < KK; k++) {
        a2 = fmaf(dW2[k],      w0[r + k], a2);
        a2 = fmaf(dW2[15 + k], w1[r + k], a2);
      }
      resf[r] = a2;
    }
    ((float4*)orow)[u] = res;
  }
}

extern "C" void kernel_launch(void* const* d_in, const int* in_sizes, int n_in,
                              void* d_out, int out_size, void* d_ws, size_t ws_size,
                              hipStream_t stream) {
  const float* x   = (const float*)d_in[0];
  const float* W1  = (const float*)d_in[1];
  const float* b1  = (const float*)d_in[2];
  const float* W2  = (const float*)d_in[3];
  const float* b2  = (const float*)d_in[4];
  const float* fcW = (const float*)d_in[5];
  const float* fcb = (const float*)d_in[6];
  const float* dW0 = (const float*)d_in[7];
  const float* db0 = (const float*)d_in[8];
  const float* dW1 = (const float*)d_in[9];
  const float* db1 = (const float*)d_in[10];
  const float* dW2 = (const float*)d_in[11];
  const float* db2 = (const float*)d_in[12];

  float* o        = (float*)d_out;
  float* out_main = o + OFF_OUT;
  float* latent   = o + OFF_LAT;
  float* sig      = o + OFF_SIG;
  float* pP  = o + OFF_P;
  float* pF  = o + OFF_F;
  float* pA  = o + OFF_A;
  float* pB0 = o + OFF_B0;

  // dynamic LDS: worst case e=7 -> 128*94 + 96 = 12128 floats = 48512 B
  const size_t lds_conv = 12128 * sizeof(float);
  conv_stack_kernel<<<dim3(EE, BB), 512, lds_conv, stream>>>(x, W1, b1, W2, b2, latent);
  fft_kernel<<<dim3(EE, BB), 512, 0, stream>>>(latent, fcW, fcb, pP, pF, pA, pB0);
  sig_deconv_kernel<<<dim3(TT/TILE_C, BB), 256, 0, stream>>>(
      pP, pF, pA, pB0, dW0, db0, dW1, db1, dW2, db2, sig, out_main);
}

// Round 4
// 349.357 us; speedup vs baseline: 1.7100x; 1.0111x over previous
//
#include <hip/hip_runtime.h>
#include <math.h>

#define TT 8192
#define BB 256
#define EE 8
#define KK 15
#define PI_F  3.14159265358979323846f
#define TPI_F 6.28318530717958647692f

// d_out flat layout (reference tuple order)
#define OFF_OUT 0
#define OFF_LAT (BB*TT)
#define OFF_SIG (OFF_LAT + BB*EE*TT)
#define OFF_P   (OFF_SIG + BB*EE*TT)
#define OFF_F   (OFF_P + BB*EE)
#define OFF_A   (OFF_F + BB*EE)
#define OFF_B0  (OFF_A + BB*EE)

// swizzle for fft LDS only
#define SWZ(i) ((i) + ((i) >> 5))

__device__ __forceinline__ float rdfl(float v) {
  return __uint_as_float(__builtin_amdgcn_readfirstlane(__float_as_uint(v)));
}

// =====================================================================
// Kernel A: composed dilated conv, HALF-ROW polyphase LDS layout.
// Grid (2, EE, BB) = 4096 blocks x 512 threads, dynamic LDS.
// Occupancy design (R3 post-mortem: 16-wave ceiling was the binder):
//   - LDS worst case (e=7): 128*62 + 96 = 8032 floats = 32.1 KB
//     -> 4+ blocks/CU.
//   - Composed weights hoisted to SGPRs via readfirstlane (block-uniform)
//     -> VGPR target <= 64 (8 waves/SIMD bucket). NO min-waves bound
//     (R2 spill disaster).
// sxp[ph*Lp + n] = x[h*4096 - 14d + ph + n*d]; thread's 29-tap dilated
// window is CONTIGUOUS. Lp == 30 (mod 32) (conflict-light, measured).
// Edge corrections only at TRUE row edges (h==0 first / h==1 last),
// computed inline from win[] regs (2 transient regs, sW read from LDS).
// =====================================================================
__global__ __launch_bounds__(512) void conv_stack_kernel(
    const float* __restrict__ x, const float* __restrict__ W1,
    const float* __restrict__ b1, const float* __restrict__ W2,
    const float* __restrict__ b2, float* __restrict__ latent)
{
  extern __shared__ float smem[];
  const int h = blockIdx.x;                 // half-row tile
  const int e = blockIdx.y, b = blockIdx.z;
  const int d  = 1 << e;
  const int Mh = (TT/2) >> e;               // outputs per phase, this tile
  // smallest Lp >= Mh+28 with Lp == 30 (mod 32)
  const int Lp = ((((Mh - 2) + 31) >> 5) << 5) + 30;
  float* sxp = smem;                        // d*Lp floats
  float* sW  = smem + d * Lp;               // 96 floats
  const int tid = threadIdx.x;
  const float* xr = x + b * TT;
  const int tbase = h * (TT/2) - 14 * d;

  // ---- stage half x row (+14d halo each side) into polyphase layout
  const int nstage = (TT/2) + 28 * d;
  for (int i = tid; i < nstage; i += 512) {
    int t  = tbase + i;
    int ph = i & (d - 1);
    int n  = i >> e;
    sxp[ph * Lp + n] = (t >= 0 && t < TT) ? xr[t] : 0.0f;
  }

  // ---- weights: composed 29-tap + raw
  if (tid < 29) {
    float acc = 0.0f;
    for (int c = 0; c < 2; c++) {
      const float* w1 = W1 + e*30 + c*15;
      const float* w2 = W2 + e*30 + c*15;
      int jlo = tid - 14; if (jlo < 0) jlo = 0;
      int jhi = tid;      if (jhi > 14) jhi = 14;
      for (int j = jlo; j <= jhi; j++) acc += w2[j] * w1[tid - j];
    }
    sW[tid] = acc;
  } else if (tid == 29) {
    float s20 = 0.f, s21 = 0.f;
    for (int j = 0; j < 15; j++) { s20 += W2[e*30 + j]; s21 += W2[e*30 + 15 + j]; }
    sW[29] = b2[e] + s20*b1[e*2] + s21*b1[e*2 + 1];
  } else if (tid >= 32 && tid < 62) {
    sW[tid] = W1[e*30 + (tid - 32)];
  } else if (tid >= 64 && tid < 94) {
    sW[tid] = W2[e*30 + (tid - 64)];
  } else if (tid == 94 || tid == 95) {
    sW[tid] = b1[e*2 + (tid - 94)];
  }
  __syncthreads();

  // ---- composed weights -> SGPRs (block-uniform)
  float Wc[29];
  #pragma unroll
  for (int s = 0; s < 29; s++) Wc[s] = rdfl(sW[s]);
  const float Bc = rdfl(sW[29]);

  // ---- main composed conv: 2 groups of 4 chain outputs per thread
  float* lr = latent + (b * EE + e) * TT + h * (TT/2);
  #pragma unroll 1
  for (int g = 0; g < 2; g++) {
    const int vt = g * 512 + tid;            // virtual thread 0..1023
    const int ph = vt & (d - 1);
    const int m0 = (vt >> e) << 2;           // phase-local first output index

    float win[32];
    {
      const float2* wp = (const float2*)&sxp[ph * Lp + m0];
      #pragma unroll
      for (int v = 0; v < 16; v++) {
        float2 qv = wp[v];
        win[2*v] = qv.x; win[2*v+1] = qv.y;
      }
    }
    float acc[4] = {Bc, Bc, Bc, Bc};
    #pragma unroll
    for (int s = 0; s < 29; s++) {
      #pragma unroll
      for (int r = 0; r < 4; r++) acc[r] = fmaf(Wc[s], win[s + r], acc[r]);
    }

    // ---- first-edge correction (true row start: h==0, g==0)
    if (h == 0 && g == 0 && m0 <= 6) {
      #pragma unroll
      for (int r = 0; r < 4; r++) {
        float corr = 0.0f;
        #pragma unroll
        for (int j = 0; j < 7; j++) {
          if (m0 + r + j <= 6) {
            float a0 = sW[94], a1 = sW[95];
            #pragma unroll
            for (int k = 0; k < 15; k++) {
              float xv = win[r + j + k];
              a0 = fmaf(sW[32 + k], xv, a0);
              a1 = fmaf(sW[47 + k], xv, a1);
            }
            corr = fmaf(sW[64 + j], a0, corr);
            corr = fmaf(sW[79 + j], a1, corr);
          }
        }
        acc[r] -= corr;
      }
    }
    // ---- last-edge correction (true row end: h==1, g==1)
    if (h == 1 && g == 1 && m0 + 3 >= Mh - 7) {
      #pragma unroll
      for (int r = 0; r < 4; r++) {
        float corr = 0.0f;
        #pragma unroll
        for (int jj = 0; jj < 7; jj++) {
          const int j = 8 + jj;
          if (m0 + r + j >= Mh + 7) {
            float a0 = sW[94], a1 = sW[95];
            #pragma unroll
            for (int k = 0; k < 15; k++) {
              float xv = win[r + j + k];
              a0 = fmaf(sW[32 + k], xv, a0);
              a1 = fmaf(sW[47 + k], xv, a1);
            }
            corr = fmaf(sW[64 + j], a0, corr);
            corr = fmaf(sW[79 + j], a1, corr);
          }
        }
        acc[r] -= corr;
      }
    }

    #pragma unroll
    for (int r = 0; r < 4; r++) lr[ph + (m0 + r) * d] = acc[r];
  }
}

// =====================================================================
// Kernel B: real-packed FFT (N=4096 radix-4) + moments + fc phase.
// 512 threads; native __sinf/__cosf only (no slow-path sincos).
// =====================================================================
#define NF 4096

__device__ __forceinline__ int rev4(int k) {   // base-4 digit reversal, 6 digits
  unsigned r = __brev((unsigned)k) >> 20;      // 12-bit bit reversal
  return (int)(((r & 0x555u) << 1) | ((r >> 1) & 0x555u));
}

__global__ __launch_bounds__(512) void fft_kernel(
    const float* __restrict__ latent, const float* __restrict__ fcW,
    const float* __restrict__ fcb, float* __restrict__ outP,
    float* __restrict__ outF, float* __restrict__ outA, float* __restrict__ outB0)
{
  __shared__ float re[SWZ(NF - 1) + 1];
  __shared__ float im[SWZ(NF - 1) + 1];
  __shared__ float rbuf[32];
  const int e = blockIdx.x, b = blockIdx.y, tid = threadIdx.x;
  const float2* row2 = (const float2*)(latent + (b*EE + e)*TT);
  const float2* f02  = (const float2*)(fcW + (e*2 + 0)*TT);
  const float2* f12  = (const float2*)(fcW + (e*2 + 1)*TT);

  float v0 = 0.f, v1 = 0.f;
  for (int n = tid; n < NF; n += 512) {
    float2 z = row2[n];
    re[SWZ(n)] = z.x; im[SWZ(n)] = z.y;
    float2 a0 = f02[n], a1 = f12[n];
    v0 = fmaf(z.x, a0.x, v0); v0 = fmaf(z.y, a0.y, v0);
    v1 = fmaf(z.x, a1.x, v1); v1 = fmaf(z.y, a1.y, v1);
  }
  __syncthreads();

  for (int L = NF >> 2; L >= 1; L >>= 2) {
    float wstep = -1.57079632679f / (float)L;
    for (int u = tid; u < (NF >> 2); u += 512) {
      int p = u & (L - 1);
      int base = ((u - p) << 2) + p;
      int i0 = SWZ(base), i1 = SWZ(base + L), i2 = SWZ(base + 2*L), i3 = SWZ(base + 3*L);
      float ar = re[i0], ai = im[i0];
      float br = re[i1], bi = im[i1];
      float cr = re[i2], ci = im[i2];
      float dr = re[i3], di = im[i3];
      float t0r = ar + cr, t0i = ai + ci;
      float t1r = ar - cr, t1i = ai - ci;
      float t2r = br + dr, t2i = bi + di;
      float t3r = br - dr, t3i = bi - di;
      float A0r = t0r + t2r, A0i = t0i + t2i;
      float A1r = t1r + t3i, A1i = t1i - t3r;
      float A2r = t0r - t2r, A2i = t0i - t2i;
      float A3r = t1r - t3i, A3i = t1i + t3r;
      float ang = wstep * (float)p;
      float s1 = __sinf(ang), c1 = __cosf(ang);
      float c2 = c1*c1 - s1*s1, s2 = 2.f*c1*s1;
      float c3 = c1*c2 - s1*s2, s3 = c1*s2 + s1*c2;
      re[i0] = A0r;                 im[i0] = A0i;
      re[i1] = A1r*c1 - A1i*s1;     im[i1] = A1r*s1 + A1i*c1;
      re[i2] = A2r*c2 - A2i*s2;     im[i2] = A2r*s2 + A2i*c2;
      re[i3] = A3r*c3 - A3i*s3;     im[i3] = A3r*s3 + A3i*c3;
    }
    __syncthreads();
  }

  float pacc = 0.f, facc = 0.f;
  for (int k = 1 + tid; k < NF; k += 512) {
    int jk = SWZ(rev4(k));
    int jm = SWZ(rev4(NF - k));
    float zr = re[jk], zi = im[jk];
    float yr = re[jm], yi = im[jm];
    float Er = 0.5f*(zr + yr), Ei = 0.5f*(zi - yi);
    float Dr = 0.5f*(zr - yr), Di = 0.5f*(zi + yi);
    float Or = Di, Oi = -Dr;
    float ang = -PI_F * (float)k / (float)NF;
    float s = __sinf(ang), c = __cosf(ang);
    float Xr = Er + c*Or - s*Oi;
    float Xi = Ei + c*Oi + s*Or;
    float mag = fmaf(Xr, Xr, Xi*Xi);
    pacc += mag;
    facc = fmaf(0.5f * (float)k, mag, facc);
  }
  if (tid == 0) {
    float X = re[SWZ(0)] - im[SWZ(0)];
    pacc += X*X;
    facc += 2048.0f * X*X;
  }

  #pragma unroll
  for (int off = 32; off > 0; off >>= 1) {
    pacc += __shfl_down(pacc, off);
    facc += __shfl_down(facc, off);
    v0   += __shfl_down(v0, off);
    v1   += __shfl_down(v1, off);
  }
  int wid = tid >> 6, lane = tid & 63;
  if (lane == 0) {
    rbuf[wid*4 + 0] = pacc; rbuf[wid*4 + 1] = facc;
    rbuf[wid*4 + 2] = v0;   rbuf[wid*4 + 3] = v1;
  }
  __syncthreads();
  if (tid == 0) {
    float P = 0.f, Fw = 0.f, V0 = 0.f, V1 = 0.f;
    #pragma unroll
    for (int w = 0; w < 8; w++) {
      P += rbuf[w*4]; Fw += rbuf[w*4+1]; V0 += rbuf[w*4+2]; V1 += rbuf[w*4+3];
    }
    float z0r = re[SWZ(0)], z0i = im[SWZ(0)];
    float amp  = 2.0f * sqrtf(P) / (float)TT;
    float boff = (z0r + z0i) / (float)TT;
    float vv0 = V0 + fcb[e*2 + 0];
    float vv1 = V1 + fcb[e*2 + 1];
    float ph  = atan2f(vv1, vv0) / TPI_F;
    int idx = b*EE + e;
    outP[idx]  = ph;
    outF[idx]  = Fw / P;
    outA[idx]  = amp;
    outB0[idx] = boff;
  }
}

// =====================================================================
// Kernel C: sinusoid reconstruction + fused deconv tree.
// TILE_C=512: smem 26.5 KB -> 6 blocks/CU (24 waves, was 12 at 51 KB).
// =====================================================================
#define TILE_C 512
#define SST 556     // 512 + 44 halo (21 each side), float4-rounded
#define SL0 544     // 512 + 28 + pad
#define SL1 528     // 512 + 14 + pad

__global__ __launch_bounds__(256) void sig_deconv_kernel(
    const float* __restrict__ Pv, const float* __restrict__ Fv,
    const float* __restrict__ Av, const float* __restrict__ B0v,
    const float* __restrict__ dW0, const float* __restrict__ db0,
    const float* __restrict__ dW1, const float* __restrict__ db1,
    const float* __restrict__ dW2, const float* __restrict__ db2,
    float* __restrict__ sig, float* __restrict__ out)
{
  __shared__ float smem[4*SL0 + 8*SST];
  float* sl0  = smem;
  float* ssig = smem + 4*SL0;
  float* sl1  = smem + 4*SL0;   // overlays ssig after level 0

  const int tile = blockIdx.x, b = blockIdx.y;
  const int t0 = tile * TILE_C;
  const int tid = threadIdx.x;
  const float step = 2.0f / 8191.0f;

  // ---- per-channel params (uniform -> SGPRs)
  float fs[8], am[8], psh[8], bo[8];
  #pragma unroll
  for (int ch = 0; ch < EE; ch++) {
    int idx = b*EE + ch;
    fs[ch] = Fv[idx]; am[ch] = Av[idx]; psh[ch] = Pv[idx]; bo[ch] = B0v[idx];
  }

  // ---- sinusoid generation, all channels in one flattened loop
  for (int i = tid; i < SST; i += 256) {
    int t = t0 + i - 21;
    bool in = (i < 554 && t >= 0 && t < TT);
    float arg = fmaf(step, (float)t, -1.0f);
    bool wr = (i >= 21 && i < 21 + TILE_C);
    #pragma unroll
    for (int ch = 0; ch < EE; ch++) {
      float rr = fmaf(fs[ch], arg, psh[ch]);
      rr -= rintf(rr);
      float val = in ? fmaf(am[ch], __sinf(TPI_F * rr), bo[ch]) : 0.0f;
      ssig[ch*SST + i] = val;
      if (wr) sig[(b*EE + ch)*TT + t] = val;
    }
  }
  __syncthreads();

  // ---- level 0: 8 -> 4 channels (outputs i0 < 540)
  for (int g = 0; g < 4; g++) {
    float bg = db0[g];
    for (int u = tid; u < 135; u += 256) {
      const float4* p0 = (const float4*)(ssig + (2*g)*SST + 4*u);
      const float4* p1 = (const float4*)(ssig + (2*g+1)*SST + 4*u);
      float w0[20], w1[20];
      #pragma unroll
      for (int v = 0; v < 5; v++) {
        float4 q0 = p0[v], q1 = p1[v];
        w0[4*v]=q0.x; w0[4*v+1]=q0.y; w0[4*v+2]=q0.z; w0[4*v+3]=q0.w;
        w1[4*v]=q1.x; w1[4*v+1]=q1.y; w1[4*v+2]=q1.z; w1[4*v+3]=q1.w;
      }
      #pragma unroll
      for (int r = 0; r < 4; r++) {
        int i0 = 4*u + r;
        int t = t0 + i0 - 14;
        float a2 = bg;
        #pragma unroll
        for (int k = 0; k < KK; k++) {
          a2 = fmaf(dW0[g*30 + k],      w0[r + k], a2);
          a2 = fmaf(dW0[g*30 + 15 + k], w1[r + k], a2);
        }
        sl0[g*SL0 + i0] = (t >= 0 && t < TT) ? a2 : 0.0f;
      }
    }
  }
  if (tid < 16) sl0[(tid >> 2)*SL0 + 540 + (tid & 3)] = 0.0f;  // pad tail
  __syncthreads();

  // ---- level 1: 4 -> 2 channels (outputs i1 < 526)
  for (int g = 0; g < 2; g++) {
    float bg = db1[g];
    for (int u = tid; u < 132; u += 256) {
      const float4* p0 = (const float4*)(sl0 + (2*g)*SL0 + 4*u);
      const float4* p1 = (const float4*)(sl0 + (2*g+1)*SL0 + 4*u);
      float w0[20], w1[20];
      #pragma unroll
      for (int v = 0; v < 5; v++) {
        float4 q0 = p0[v], q1 = p1[v];
        w0[4*v]=q0.x; w0[4*v+1]=q0.y; w0[4*v+2]=q0.z; w0[4*v+3]=q0.w;
        w1[4*v]=q1.x; w1[4*v+1]=q1.y; w1[4*v+2]=q1.z; w1[4*v+3]=q1.w;
      }
      #pragma unroll
      for (int r = 0; r < 4; r++) {
        int i1 = 4*u + r;
        if (i1 < 526) {
          int t = t0 + i1 - 7;
          float a2 = bg;
          #pragma unroll
          for (int k = 0; k < KK; k++) {
            a2 = fmaf(dW1[g*30 + k],      w0[r + k], a2);
            a2 = fmaf(dW1[g*30 + 15 + k], w1[r + k], a2);
          }
          sl1[g*SL1 + i1] = (t >= 0 && t < TT) ? a2 : 0.0f;
        }
      }
    }
  }
  __syncthreads();

  // ---- level 2: 2 -> 1 channel (512 outputs, 128 float4 stores)
  if (tid < 128) {
    float bg = db2[0];
    float* orow = out + b*TT + t0;
    int u = tid;
    const float4* p0 = (const float4*)(sl1 + 4*u);
    const float4* p1 = (const float4*)(sl1 + SL1 + 4*u);
    float w0[20], w1[20];
    #pragma unroll
    for (int v = 0; v < 5; v++) {
      float4 q0 = p0[v], q1 = p1[v];
      w0[4*v]=q0.x; w0[4*v+1]=q0.y; w0[4*v+2]=q0.z; w0[4*v+3]=q0.w;
      w1[4*v]=q1.x; w1[4*v+1]=q1.y; w1[4*v+2]=q1.z; w1[4*v+3]=q1.w;
    }
    float4 res;
    float* resf = (float*)&res;
    #pragma unroll
    for (int r = 0; r < 4; r++) {
      float a2 = bg;
      #pragma unroll
      for (int k = 0; k < KK; k++) {
        a2 = fmaf(dW2[k],      w0[r + k], a2);
        a2 = fmaf(dW2[15 + k], w1[r + k], a2);
      }
      resf[r] = a2;
    }
    ((float4*)orow)[u] = res;
  }
}

extern "C" void kernel_launch(void* const* d_in, const int* in_sizes, int n_in,
                              void* d_out, int out_size, void* d_ws, size_t ws_size,
                              hipStream_t stream) {
  const float* x   = (const float*)d_in[0];
  const float* W1  = (const float*)d_in[1];
  const float* b1  = (const float*)d_in[2];
  const float* W2  = (const float*)d_in[3];
  const float* b2  = (const float*)d_in[4];
  const float* fcW = (const float*)d_in[5];
  const float* fcb = (const float*)d_in[6];
  const float* dW0 = (const float*)d_in[7];
  const float* db0 = (const float*)d_in[8];
  const float* dW1 = (const float*)d_in[9];
  const float* db1 = (const float*)d_in[10];
  const float* dW2 = (const float*)d_in[11];
  const float* db2 = (const float*)d_in[12];

  float* o        = (float*)d_out;
  float* out_main = o + OFF_OUT;
  float* latent   = o + OFF_LAT;
  float* sig      = o + OFF_SIG;
  float* pP  = o + OFF_P;
  float* pF  = o + OFF_F;
  float* pA  = o + OFF_A;
  float* pB0 = o + OFF_B0;

  // dynamic LDS: max over e of d*Lp + 96 = e=7: 128*62 + 96 = 8032 floats
  const size_t lds_conv = 8032 * sizeof(float);   // 32128 B -> 4+ blocks/CU
  conv_stack_kernel<<<dim3(2, EE, BB), 512, lds_conv, stream>>>(x, W1, b1, W2, b2, latent);
  fft_kernel<<<dim3(EE, BB), 512, 0, stream>>>(latent, fcW, fcb, pP, pF, pA, pB0);
  sig_deconv_kernel<<<dim3(TT/TILE_C, BB), 256, 0, stream>>>(
      pP, pF, pA, pB0, dW0, db0, dW1, db1, dW2, db2, sig, out_main);
}

// Round 5
// 343.657 us; speedup vs baseline: 1.7383x; 1.0166x over previous
//
#include <hip/hip_runtime.h>
#include <math.h>

#define TT 8192
#define BB 256
#define EE 8
#define KK 15
#define PI_F  3.14159265358979323846f
#define TPI_F 6.28318530717958647692f

// d_out flat layout (reference tuple order)
#define OFF_OUT 0
#define OFF_LAT (BB*TT)
#define OFF_SIG (OFF_LAT + BB*EE*TT)
#define OFF_P   (OFF_SIG + BB*EE*TT)
#define OFF_F   (OFF_P + BB*EE)
#define OFF_A   (OFF_F + BB*EE)
#define OFF_B0  (OFF_A + BB*EE)

// swizzle for fft LDS only
#define SWZ(i) ((i) + ((i) >> 5))
#define NF 4096

// fused-kernel LDS layout (floats). re/im: SWZ(4095)+1 = 4223 each.
#define L_RE   0
#define L_IM   4223
#define L_SXP  8446        // max half-row polyphase: e=7 -> 128*62 = 7936
#define L_SW   16382       // 96 floats
#define L_RBUF 16478       // 32 floats
#define L_TOT  16510       // 66040 B -> 2 blocks/CU

__device__ __forceinline__ float rdfl(float v) {
  return __uint_as_float(__builtin_amdgcn_readfirstlane(__float_as_uint(v)));
}

__device__ __forceinline__ int rev4(int k) {   // base-4 digit reversal, 6 digits
  unsigned r = __brev((unsigned)k) >> 20;      // 12-bit bit reversal
  return (int)(((r & 0x555u) << 1) | ((r >> 1) & 0x555u));
}

// =====================================================================
// FUSED Kernel A+B: composed dilated conv -> real-packed FFT -> moments
// + fc phase, all in one block per (e, b). 2048 blocks x 512 threads.
//
// Conv phase: R4's verified half-row polyphase structure as an inner
// h-loop (Lp == 30 mod 32, SGPR-hoisted composed weights, inline edge
// corrections at true row edges). Each output acc[r] is stored to
// global latent AND scattered into the FFT's re/im LDS arrays
// (t -> (t&1 ? im : re)[SWZ(t>>1)]) -- the same real-packing the old
// fft kernel built by re-reading latent from global (67 MB saved, one
// kernel launch + device-wide sync removed; conv-phase of block i+1
// overlaps fft-phase of block i at 2 blocks/CU).
// =====================================================================
__global__ __launch_bounds__(512) void conv_fft_kernel(
    const float* __restrict__ x, const float* __restrict__ W1,
    const float* __restrict__ b1, const float* __restrict__ W2,
    const float* __restrict__ b2, const float* __restrict__ fcW,
    const float* __restrict__ fcb, float* __restrict__ latent,
    float* __restrict__ outP, float* __restrict__ outF,
    float* __restrict__ outA, float* __restrict__ outB0)
{
  extern __shared__ float smem[];
  float* re   = smem + L_RE;
  float* im   = smem + L_IM;
  float* sxp  = smem + L_SXP;
  float* sW   = smem + L_SW;
  float* rbuf = smem + L_RBUF;

  const int e = blockIdx.x, b = blockIdx.y;
  const int d  = 1 << e;
  const int Mh = (TT/2) >> e;               // outputs per phase per half
  // smallest Lp >= Mh+28 with Lp == 30 (mod 32)
  const int Lp = ((((Mh - 2) + 31) >> 5) << 5) + 30;
  const int tid = threadIdx.x;
  const float* xr = x + b * TT;

  // ---- weights: composed 29-tap + raw (written once, before 1st barrier)
  if (tid < 29) {
    float acc = 0.0f;
    for (int c = 0; c < 2; c++) {
      const float* w1 = W1 + e*30 + c*15;
      const float* w2 = W2 + e*30 + c*15;
      int jlo = tid - 14; if (jlo < 0) jlo = 0;
      int jhi = tid;      if (jhi > 14) jhi = 14;
      for (int j = jlo; j <= jhi; j++) acc += w2[j] * w1[tid - j];
    }
    sW[tid] = acc;
  } else if (tid == 29) {
    float s20 = 0.f, s21 = 0.f;
    for (int j = 0; j < 15; j++) { s20 += W2[e*30 + j]; s21 += W2[e*30 + 15 + j]; }
    sW[29] = b2[e] + s20*b1[e*2] + s21*b1[e*2 + 1];
  } else if (tid >= 32 && tid < 62) {
    sW[tid] = W1[e*30 + (tid - 32)];
  } else if (tid >= 64 && tid < 94) {
    sW[tid] = W2[e*30 + (tid - 64)];
  } else if (tid == 94 || tid == 95) {
    sW[tid] = b1[e*2 + (tid - 94)];
  }

  float Wc[29];
  float Bc = 0.0f;
  bool wloaded = false;

  #pragma unroll 1
  for (int h = 0; h < 2; ++h) {
    // ---- stage half x row (+14d halo each side) into polyphase layout
    const int tbase = h * (TT/2) - 14 * d;
    const int nstage = (TT/2) + 28 * d;
    for (int i = tid; i < nstage; i += 512) {
      int t  = tbase + i;
      int ph = i & (d - 1);
      int n  = i >> e;
      sxp[ph * Lp + n] = (t >= 0 && t < TT) ? xr[t] : 0.0f;
    }
    __syncthreads();

    if (!wloaded) {          // composed weights -> SGPRs (block-uniform)
      #pragma unroll
      for (int s = 0; s < 29; s++) Wc[s] = rdfl(sW[s]);
      Bc = rdfl(sW[29]);
      wloaded = true;
    }

    float* lr = latent + (b * EE + e) * TT + h * (TT/2);

    #pragma unroll 1
    for (int g = 0; g < 2; g++) {
      const int vt = g * 512 + tid;            // virtual thread 0..1023
      const int ph = vt & (d - 1);
      const int m0 = (vt >> e) << 2;           // phase-local first output idx

      float win[32];
      {
        const float2* wp = (const float2*)&sxp[ph * Lp + m0];
        #pragma unroll
        for (int v = 0; v < 16; v++) {
          float2 qv = wp[v];
          win[2*v] = qv.x; win[2*v+1] = qv.y;
        }
      }
      float acc[4] = {Bc, Bc, Bc, Bc};
      #pragma unroll
      for (int s = 0; s < 29; s++) {
        #pragma unroll
        for (int r = 0; r < 4; r++) acc[r] = fmaf(Wc[s], win[s + r], acc[r]);
      }

      // ---- first-edge correction (true row start: h==0, g==0)
      if (h == 0 && g == 0 && m0 <= 6) {
        #pragma unroll
        for (int r = 0; r < 4; r++) {
          float corr = 0.0f;
          #pragma unroll
          for (int j = 0; j < 7; j++) {
            if (m0 + r + j <= 6) {
              float a0 = sW[94], a1 = sW[95];
              #pragma unroll
              for (int k = 0; k < 15; k++) {
                float xv = win[r + j + k];
                a0 = fmaf(sW[32 + k], xv, a0);
                a1 = fmaf(sW[47 + k], xv, a1);
              }
              corr = fmaf(sW[64 + j], a0, corr);
              corr = fmaf(sW[79 + j], a1, corr);
            }
          }
          acc[r] -= corr;
        }
      }
      // ---- last-edge correction (true row end: h==1, g==1)
      if (h == 1 && g == 1 && m0 + 3 >= Mh - 7) {
        #pragma unroll
        for (int r = 0; r < 4; r++) {
          float corr = 0.0f;
          #pragma unroll
          for (int jj = 0; jj < 7; jj++) {
            const int j = 8 + jj;
            if (m0 + r + j >= Mh + 7) {
              float a0 = sW[94], a1 = sW[95];
              #pragma unroll
              for (int k = 0; k < 15; k++) {
                float xv = win[r + j + k];
                a0 = fmaf(sW[32 + k], xv, a0);
                a1 = fmaf(sW[47 + k], xv, a1);
              }
              corr = fmaf(sW[64 + j], a0, corr);
              corr = fmaf(sW[79 + j], a1, corr);
            }
          }
          acc[r] -= corr;
        }
      }

      // ---- store to global latent + scatter real-packed into re/im LDS
      #pragma unroll
      for (int r = 0; r < 4; r++) {
        int toff = ph + (m0 + r) * d;
        lr[toff] = acc[r];
        int tg = h * (TT/2) + toff;
        int n  = tg >> 1;
        float* dst = (tg & 1) ? im : re;
        dst[SWZ(n)] = acc[r];
      }
    }
    __syncthreads();   // sxp consumed (safe to overwrite next h); scatter visible
  }

  // ---- fc dot-product pass: latent (from LDS) x fcW (global, coalesced)
  const float2* f02 = (const float2*)(fcW + (e*2 + 0)*TT);
  const float2* f12 = (const float2*)(fcW + (e*2 + 1)*TT);
  float v0 = 0.f, v1 = 0.f;
  for (int n = tid; n < NF; n += 512) {
    float zr = re[SWZ(n)], zi = im[SWZ(n)];
    float2 a0 = f02[n], a1 = f12[n];
    v0 = fmaf(zr, a0.x, v0); v0 = fmaf(zi, a0.y, v0);
    v1 = fmaf(zr, a1.x, v1); v1 = fmaf(zi, a1.y, v1);
  }
  __syncthreads();   // fc reads done before in-place butterfly writes

  // ---- radix-4 DIF stages (N=4096 complex, in place, SWZ'd)
  for (int L = NF >> 2; L >= 1; L >>= 2) {
    float wstep = -1.57079632679f / (float)L;
    for (int u = tid; u < (NF >> 2); u += 512) {
      int p = u & (L - 1);
      int base = ((u - p) << 2) + p;
      int i0 = SWZ(base), i1 = SWZ(base + L), i2 = SWZ(base + 2*L), i3 = SWZ(base + 3*L);
      float ar = re[i0], ai = im[i0];
      float br = re[i1], bi = im[i1];
      float cr = re[i2], ci = im[i2];
      float dr = re[i3], di = im[i3];
      float t0r = ar + cr, t0i = ai + ci;
      float t1r = ar - cr, t1i = ai - ci;
      float t2r = br + dr, t2i = bi + di;
      float t3r = br - dr, t3i = bi - di;
      float A0r = t0r + t2r, A0i = t0i + t2i;
      float A1r = t1r + t3i, A1i = t1i - t3r;
      float A2r = t0r - t2r, A2i = t0i - t2i;
      float A3r = t1r - t3i, A3i = t1i + t3r;
      float ang = wstep * (float)p;
      float s1 = __sinf(ang), c1 = __cosf(ang);
      float c2 = c1*c1 - s1*s1, s2 = 2.f*c1*s1;
      float c3 = c1*c2 - s1*s2, s3 = c1*s2 + s1*c2;
      re[i0] = A0r;                 im[i0] = A0i;
      re[i1] = A1r*c1 - A1i*s1;     im[i1] = A1r*s1 + A1i*c1;
      re[i2] = A2r*c2 - A2i*s2;     im[i2] = A2r*s2 + A2i*c2;
      re[i3] = A3r*c3 - A3i*s3;     im[i3] = A3r*s3 + A3i*c3;
    }
    __syncthreads();
  }

  // ---- moments over unpacked real spectrum
  float pacc = 0.f, facc = 0.f;
  for (int k = 1 + tid; k < NF; k += 512) {
    int jk = SWZ(rev4(k));
    int jm = SWZ(rev4(NF - k));
    float zr = re[jk], zi = im[jk];
    float yr = re[jm], yi = im[jm];
    float Er = 0.5f*(zr + yr), Ei = 0.5f*(zi - yi);
    float Dr = 0.5f*(zr - yr), Di = 0.5f*(zi + yi);
    float Or = Di, Oi = -Dr;
    float ang = -PI_F * (float)k / (float)NF;
    float s = __sinf(ang), c = __cosf(ang);
    float Xr = Er + c*Or - s*Oi;
    float Xi = Ei + c*Oi + s*Or;
    float mag = fmaf(Xr, Xr, Xi*Xi);
    pacc += mag;
    facc = fmaf(0.5f * (float)k, mag, facc);
  }
  if (tid == 0) {
    float X = re[SWZ(0)] - im[SWZ(0)];
    pacc += X*X;
    facc += 2048.0f * X*X;
  }

  #pragma unroll
  for (int off = 32; off > 0; off >>= 1) {
    pacc += __shfl_down(pacc, off);
    facc += __shfl_down(facc, off);
    v0   += __shfl_down(v0, off);
    v1   += __shfl_down(v1, off);
  }
  int wid = tid >> 6, lane = tid & 63;
  if (lane == 0) {
    rbuf[wid*4 + 0] = pacc; rbuf[wid*4 + 1] = facc;
    rbuf[wid*4 + 2] = v0;   rbuf[wid*4 + 3] = v1;
  }
  __syncthreads();
  if (tid == 0) {
    float P = 0.f, Fw = 0.f, V0 = 0.f, V1 = 0.f;
    #pragma unroll
    for (int w = 0; w < 8; w++) {
      P += rbuf[w*4]; Fw += rbuf[w*4+1]; V0 += rbuf[w*4+2]; V1 += rbuf[w*4+3];
    }
    float z0r = re[SWZ(0)], z0i = im[SWZ(0)];
    float amp  = 2.0f * sqrtf(P) / (float)TT;
    float boff = (z0r + z0i) / (float)TT;
    float vv0 = V0 + fcb[e*2 + 0];
    float vv1 = V1 + fcb[e*2 + 1];
    float ph  = atan2f(vv1, vv0) / TPI_F;
    int idx = b*EE + e;
    outP[idx]  = ph;
    outF[idx]  = Fw / P;
    outA[idx]  = amp;
    outB0[idx] = boff;
  }
}

// =====================================================================
// Kernel C: sinusoid reconstruction + fused deconv tree.
// TILE_C=512: smem 26.5 KB -> 6 blocks/CU.
// =====================================================================
#define TILE_C 512
#define SST 556     // 512 + 44 halo (21 each side), float4-rounded
#define SL0 544     // 512 + 28 + pad
#define SL1 528     // 512 + 14 + pad

__global__ __launch_bounds__(256) void sig_deconv_kernel(
    const float* __restrict__ Pv, const float* __restrict__ Fv,
    const float* __restrict__ Av, const float* __restrict__ B0v,
    const float* __restrict__ dW0, const float* __restrict__ db0,
    const float* __restrict__ dW1, const float* __restrict__ db1,
    const float* __restrict__ dW2, const float* __restrict__ db2,
    float* __restrict__ sig, float* __restrict__ out)
{
  __shared__ float smem[4*SL0 + 8*SST];
  float* sl0  = smem;
  float* ssig = smem + 4*SL0;
  float* sl1  = smem + 4*SL0;   // overlays ssig after level 0

  const int tile = blockIdx.x, b = blockIdx.y;
  const int t0 = tile * TILE_C;
  const int tid = threadIdx.x;
  const float step = 2.0f / 8191.0f;

  // ---- per-channel params (uniform -> SGPRs)
  float fs[8], am[8], psh[8], bo[8];
  #pragma unroll
  for (int ch = 0; ch < EE; ch++) {
    int idx = b*EE + ch;
    fs[ch] = Fv[idx]; am[ch] = Av[idx]; psh[ch] = Pv[idx]; bo[ch] = B0v[idx];
  }

  // ---- sinusoid generation, all channels in one flattened loop
  for (int i = tid; i < SST; i += 256) {
    int t = t0 + i - 21;
    bool in = (i < 554 && t >= 0 && t < TT);
    float arg = fmaf(step, (float)t, -1.0f);
    bool wr = (i >= 21 && i < 21 + TILE_C);
    #pragma unroll
    for (int ch = 0; ch < EE; ch++) {
      float rr = fmaf(fs[ch], arg, psh[ch]);
      rr -= rintf(rr);
      float val = in ? fmaf(am[ch], __sinf(TPI_F * rr), bo[ch]) : 0.0f;
      ssig[ch*SST + i] = val;
      if (wr) sig[(b*EE + ch)*TT + t] = val;
    }
  }
  __syncthreads();

  // ---- level 0: 8 -> 4 channels (outputs i0 < 540)
  for (int g = 0; g < 4; g++) {
    float bg = db0[g];
    for (int u = tid; u < 135; u += 256) {
      const float4* p0 = (const float4*)(ssig + (2*g)*SST + 4*u);
      const float4* p1 = (const float4*)(ssig + (2*g+1)*SST + 4*u);
      float w0[20], w1[20];
      #pragma unroll
      for (int v = 0; v < 5; v++) {
        float4 q0 = p0[v], q1 = p1[v];
        w0[4*v]=q0.x; w0[4*v+1]=q0.y; w0[4*v+2]=q0.z; w0[4*v+3]=q0.w;
        w1[4*v]=q1.x; w1[4*v+1]=q1.y; w1[4*v+2]=q1.z; w1[4*v+3]=q1.w;
      }
      #pragma unroll
      for (int r = 0; r < 4; r++) {
        int i0 = 4*u + r;
        int t = t0 + i0 - 14;
        float a2 = bg;
        #pragma unroll
        for (int k = 0; k < KK; k++) {
          a2 = fmaf(dW0[g*30 + k],      w0[r + k], a2);
          a2 = fmaf(dW0[g*30 + 15 + k], w1[r + k], a2);
        }
        sl0[g*SL0 + i0] = (t >= 0 && t < TT) ? a2 : 0.0f;
      }
    }
  }
  if (tid < 16) sl0[(tid >> 2)*SL0 + 540 + (tid & 3)] = 0.0f;  // pad tail
  __syncthreads();

  // ---- level 1: 4 -> 2 channels (outputs i1 < 526)
  for (int g = 0; g < 2; g++) {
    float bg = db1[g];
    for (int u = tid; u < 132; u += 256) {
      const float4* p0 = (const float4*)(sl0 + (2*g)*SL0 + 4*u);
      const float4* p1 = (const float4*)(sl0 + (2*g+1)*SL0 + 4*u);
      float w0[20], w1[20];
      #pragma unroll
      for (int v = 0; v < 5; v++) {
        float4 q0 = p0[v], q1 = p1[v];
        w0[4*v]=q0.x; w0[4*v+1]=q0.y; w0[4*v+2]=q0.z; w0[4*v+3]=q0.w;
        w1[4*v]=q1.x; w1[4*v+1]=q1.y; w1[4*v+2]=q1.z; w1[4*v+3]=q1.w;
      }
      #pragma unroll
      for (int r = 0; r < 4; r++) {
        int i1 = 4*u + r;
        if (i1 < 526) {
          int t = t0 + i1 - 7;
          float a2 = bg;
          #pragma unroll
          for (int k = 0; k < KK; k++) {
            a2 = fmaf(dW1[g*30 + k],      w0[r + k], a2);
            a2 = fmaf(dW1[g*30 + 15 + k], w1[r + k], a2);
          }
          sl1[g*SL1 + i1] = (t >= 0 && t < TT) ? a2 : 0.0f;
        }
      }
    }
  }
  __syncthreads();

  // ---- level 2: 2 -> 1 channel (512 outputs, 128 float4 stores)
  if (tid < 128) {
    float bg = db2[0];
    float* orow = out + b*TT + t0;
    int u = tid;
    const float4* p0 = (const float4*)(sl1 + 4*u);
    const float4* p1 = (const float4*)(sl1 + SL1 + 4*u);
    float w0[20], w1[20];
    #pragma unroll
    for (int v = 0; v < 5; v++) {
      float4 q0 = p0[v], q1 = p1[v];
      w0[4*v]=q0.x; w0[4*v+1]=q0.y; w0[4*v+2]=q0.z; w0[4*v+3]=q0.w;
      w1[4*v]=q1.x; w1[4*v+1]=q1.y; w1[4*v+2]=q1.z; w1[4*v+3]=q1.w;
    }
    float4 res;
    float* resf = (float*)&res;
    #pragma unroll
    for (int r = 0; r < 4; r++) {
      float a2 = bg;
      #pragma unroll
      for (int k = 0; k < KK; k++) {
        a2 = fmaf(dW2[k],      w0[r + k], a2);
        a2 = fmaf(dW2[15 + k], w1[r + k], a2);
      }
      resf[r] = a2;
    }
    ((float4*)orow)[u] = res;
  }
}

extern "C" void kernel_launch(void* const* d_in, const int* in_sizes, int n_in,
                              void* d_out, int out_size, void* d_ws, size_t ws_size,
                              hipStream_t stream) {
  const float* x   = (const float*)d_in[0];
  const float* W1  = (const float*)d_in[1];
  const float* b1  = (const float*)d_in[2];
  const float* W2  = (const float*)d_in[3];
  const float* b2  = (const float*)d_in[4];
  const float* fcW = (const float*)d_in[5];
  const float* fcb = (const float*)d_in[6];
  const float* dW0 = (const float*)d_in[7];
  const float* db0 = (const float*)d_in[8];
  const float* dW1 = (const float*)d_in[9];
  const float* db1 = (const float*)d_in[10];
  const float* dW2 = (const float*)d_in[11];
  const float* db2 = (const float*)d_in[12];

  float* o        = (float*)d_out;
  float* out_main = o + OFF_OUT;
  float* latent   = o + OFF_LAT;
  float* sig      = o + OFF_SIG;
  float* pP  = o + OFF_P;
  float* pF  = o + OFF_F;
  float* pA  = o + OFF_A;
  float* pB0 = o + OFF_B0;

  const size_t lds_fused = L_TOT * sizeof(float);   // 66040 B -> 2 blocks/CU
  conv_fft_kernel<<<dim3(EE, BB), 512, lds_fused, stream>>>(
      x, W1, b1, W2, b2, fcW, fcb, latent, pP, pF, pA, pB0);
  sig_deconv_kernel<<<dim3(TT/TILE_C, BB), 256, 0, stream>>>(
      pP, pF, pA, pB0, dW0, db0, dW1, db1, dW2, db2, sig, out_main);
}